// Round 4
// baseline (608.086 us; speedup 1.0000x reference)
//
#include <hip/hip_runtime.h>
#include <hip/hip_bf16.h>
#include <cstdint>

typedef __bf16 bf16;
typedef __bf16 bf16x8 __attribute__((ext_vector_type(8)));
typedef float f32x4 __attribute__((ext_vector_type(4)));

#define DEV __device__ __forceinline__

DEV f32x4 mfma16(bf16x8 a, bf16x8 b, f32x4 c) {
  return __builtin_amdgcn_mfma_f32_16x16x32_bf16(a, b, c, 0, 0, 0);
}

DEV void gl2lds16(const void* g, void* l) {
  __builtin_amdgcn_global_load_lds((__attribute__((address_space(1))) void*)g,
                                   (__attribute__((address_space(3))) void*)l,
                                   16, 0, 0);
}

// ---------------- fused fp32 -> bf16 convert, 3 segments ----------------
DEV void cvt8(const float* __restrict__ s, bf16* __restrict__ d) {
  f32x4 a = *(const f32x4*)(s);
  f32x4 b = *(const f32x4*)(s + 4);
  bf16x8 o;
#pragma unroll
  for (int e = 0; e < 4; ++e) { o[e] = (bf16)a[e]; o[e + 4] = (bf16)b[e]; }
  *(bf16x8*)(d) = o;
}

__global__ void cvt3(const float* __restrict__ s0, bf16* __restrict__ d0, int n0,
                     const float* __restrict__ s1, bf16* __restrict__ d1, int n1,
                     const float* __restrict__ s2, bf16* __restrict__ d2) {
  long i = ((long)blockIdx.x * 256 + threadIdx.x) * 8;
  if (i < n0) { cvt8(s0 + i, d0 + i); return; }
  i -= n0;
  if (i < n1) { cvt8(s1 + i, d1 + i); return; }
  i -= n1;
  cvt8(s2 + i, d2 + i);
}

// ---------------- GEMM C = A(MxK) * B(NxK)^T ----------------
// 128x128 tile, BK=32, global_load_lds staging. SPLIT>1: blockIdx.z takes a
// K-slice and accumulates into fp32 C via atomicAdd (C must be pre-zeroed).
template <typename OutT, int SPLIT>
__global__ __launch_bounds__(256) void gemm_bt(const bf16* __restrict__ A,
                                               const bf16* __restrict__ B,
                                               OutT* __restrict__ C,
                                               int M, int N, int K) {
  __shared__ bf16 As[128 * 32];
  __shared__ bf16 Bs[128 * 32];
  const int tid = threadIdx.x;
  const int lane = tid & 63, w = tid >> 6;
  const int wm = w & 1, wn = w >> 1;
  const int quad = lane >> 4, r = lane & 15;
  const long mBase = (long)blockIdx.y * 128, nBase = (long)blockIdx.x * 128;
  const int Kh = K / SPLIT;
  const int kBeg = blockIdx.z * Kh, kEnd = kBeg + Kh;
  f32x4 acc[4][4];
#pragma unroll
  for (int i = 0; i < 4; ++i)
#pragma unroll
    for (int j = 0; j < 4; ++j) acc[i][j] = f32x4{0.f, 0.f, 0.f, 0.f};

  for (int k0 = kBeg; k0 < kEnd; k0 += 32) {
    __syncthreads();
#pragma unroll
    for (int j = 0; j < 2; ++j) {
      const int c = w * 128 + j * 64 + lane;
      const int row = c >> 2, kc = c & 3;
      gl2lds16(A + (mBase + row) * (long)K + k0 + kc * 8,
               (char*)As + (w * 128 + j * 64) * 16);
      gl2lds16(B + (nBase + row) * (long)K + k0 + kc * 8,
               (char*)Bs + (w * 128 + j * 64) * 16);
    }
    __syncthreads();
    bf16x8 af[4], bfr[4];
#pragma unroll
    for (int i = 0; i < 4; ++i) {
      af[i]  = *(const bf16x8*)(&As[(wm * 64 + i * 16 + r) * 32 + quad * 8]);
      bfr[i] = *(const bf16x8*)(&Bs[(wn * 64 + i * 16 + r) * 32 + quad * 8]);
    }
#pragma unroll
    for (int mi = 0; mi < 4; ++mi)
#pragma unroll
      for (int ni = 0; ni < 4; ++ni)
        acc[mi][ni] = mfma16(af[mi], bfr[ni], acc[mi][ni]);
  }
#pragma unroll
  for (int mi = 0; mi < 4; ++mi)
#pragma unroll
    for (int ni = 0; ni < 4; ++ni)
#pragma unroll
      for (int rg = 0; rg < 4; ++rg) {
        long row = mBase + wm * 64 + mi * 16 + quad * 4 + rg;
        long col = nBase + wn * 64 + ni * 16 + r;
        if (SPLIT > 1)
          atomicAdd((float*)&C[row * N + col], acc[mi][ni][rg]);
        else
          C[row * N + col] = (OutT)acc[mi][ni][rg];
      }
}

// ---------------- RoPE (neox), vectorized bf16x8 ----------------
__global__ void rope_kernel(bf16* __restrict__ qkv, const int* __restrict__ pos) {
  int idx = blockIdx.x * 256 + threadIdx.x;  // T*40*8 threads
  int g = idx & 7;
  int rest = idx >> 3;
  int head = rest % 40;
  int t = rest / 40;
  bf16* p = qkv + (long)t * 6144 + head * 128 + g * 8;
  bf16x8 a = *(const bf16x8*)(p);
  bf16x8 b = *(const bf16x8*)(p + 64);
  const float pf = (float)pos[t];
  bf16x8 oa, ob;
#pragma unroll
  for (int e = 0; e < 8; ++e) {
    const int d = g * 8 + e;
    const float invf = __builtin_expf(-(float)d * (9.210340371976184f / 64.0f));
    const float fr = pf * invf;
    const float c = __builtin_cosf(fr), s = __builtin_sinf(fr);
    const float x1 = (float)a[e], x2 = (float)b[e];
    oa[e] = (bf16)(x1 * c - x2 * s);
    ob[e] = (bf16)(x2 * c + x1 * s);
  }
  *(bf16x8*)(p) = oa;
  *(bf16x8*)(p + 64) = ob;
}

// ---------------- flash attention v4: double-buffered LDS, 1 barrier/tile ----------------
// grid = (16 pairs, 32 heads), 4 waves x 16 q-rows; block does q-tiles p and 31-p
// (33 kv-tiles each). Per tile: regs->LDS buf(kt&1), prefetch kt+1, ONE barrier,
// compute from buf. Writers never touch the buffer being read.
__global__ __launch_bounds__(256, 2) void attn_kernel(const bf16* __restrict__ qkv,
                                                      bf16* __restrict__ out) {
  constexpr int LDV = 72, LDP = 72;
  constexpr float SCL2 = 0.08838834764831845f * 1.4426950408889634f;  // 1/sqrt(128)*log2(e)
  __shared__ bf16 Ks[2][64 * 128];   // [kv][d], chunk-XOR (phys = logical^(row&15))
  __shared__ bf16 Vt[2][128 * LDV];  // V^T [d][kv(+pad)], col-chunk XOR
  __shared__ bf16 Ps[64 * LDP];
  const int tid = threadIdx.x;
  const int lane = tid & 63, w = tid >> 6;
  const int quad = lane >> 4, r = lane & 15;
  const int pr = blockIdx.x, h = blockIdx.y;
  const int kvh = h >> 2;

  bf16x8 kreg[4], vreg[4];
  int srow[4], sdc[4];
#pragma unroll
  for (int ii = 0; ii < 4; ++ii) {
    const int c = ii * 256 + tid;
    srow[ii] = c >> 4;
    sdc[ii] = c & 15;
  }

  for (int which = 0; which < 2; ++which) {
    const int qt = which ? (31 - pr) : pr;
    const int rowq = qt * 64 + w * 16;

    bf16x8 qf[4];
#pragma unroll
    for (int ks = 0; ks < 4; ++ks)
      qf[ks] = *(const bf16x8*)(qkv + (long)(rowq + r) * 6144 + h * 128 + ks * 32 + quad * 8);

    f32x4 of[8];
#pragma unroll
    for (int di = 0; di < 8; ++di) of[di] = f32x4{0.f, 0.f, 0.f, 0.f};
    float mrun[4], lrun[4];
#pragma unroll
    for (int rg = 0; rg < 4; ++rg) { mrun[rg] = -__builtin_inff(); lrun[rg] = 0.f; }

    const int ntiles = qt + 1;
    // prefetch tile 0 into regs
#pragma unroll
    for (int ii = 0; ii < 4; ++ii) {
      const long rb = (long)srow[ii] * 6144 + kvh * 128;
      kreg[ii] = *(const bf16x8*)(qkv + rb + 4096 + sdc[ii] * 8);
      vreg[ii] = *(const bf16x8*)(qkv + rb + 5120 + sdc[ii] * 8);
    }

    for (int kt = 0; kt < ntiles; ++kt) {
      const int kvbase = kt * 64;
      const int buf = kt & 1;
      // regs -> LDS (buffer not being read this iteration)
#pragma unroll
      for (int ii = 0; ii < 4; ++ii) {
        const int row = srow[ii], dc = sdc[ii];
        *(bf16x8*)(&Ks[buf][row * 128 + ((dc ^ (row & 15)) << 3)]) = kreg[ii];
        const int pc = (((row >> 3) ^ (dc & 7)) << 3) + (row & 7);
#pragma unroll
        for (int e = 0; e < 8; ++e) Vt[buf][(dc * 8 + e) * LDV + pc] = vreg[ii][e];
      }
      // prefetch next tile (consumed after next barrier -> full-tile latency cover)
      {
        const int kvn = (kt + 1 < ntiles) ? (kt + 1) * 64 : kt * 64;
#pragma unroll
        for (int ii = 0; ii < 4; ++ii) {
          const long rb = (long)(kvn + srow[ii]) * 6144 + kvh * 128;
          kreg[ii] = *(const bf16x8*)(qkv + rb + 4096 + sdc[ii] * 8);
          vreg[ii] = *(const bf16x8*)(qkv + rb + 5120 + sdc[ii] * 8);
        }
      }
      __syncthreads();  // the only barrier per tile

      // --- S = Q K^T
      f32x4 sacc[4];
#pragma unroll
      for (int ni = 0; ni < 4; ++ni) sacc[ni] = f32x4{0.f, 0.f, 0.f, 0.f};
#pragma unroll
      for (int ks = 0; ks < 4; ++ks) {
        bf16x8 kf[4];
#pragma unroll
        for (int ni = 0; ni < 4; ++ni)
          kf[ni] = *(const bf16x8*)(&Ks[buf][(ni * 16 + r) * 128 + (((ks * 4 + quad) ^ r) << 3)]);
#pragma unroll
        for (int ni = 0; ni < 4; ++ni) sacc[ni] = mfma16(qf[ks], kf[ni], sacc[ni]);
      }

      // --- mask (diagonal tile only) + row max
      float mt[4];
#pragma unroll
      for (int rg = 0; rg < 4; ++rg) mt[rg] = -1e30f;
      if (kt == qt) {
        const int rq = rowq + quad * 4;
#pragma unroll
        for (int ni = 0; ni < 4; ++ni) {
          const int ck = kvbase + ni * 16 + r;
#pragma unroll
          for (int rg = 0; rg < 4; ++rg) {
            float sv = sacc[ni][rg];
            sv = (ck > rq + rg) ? -1e30f : sv;
            sacc[ni][rg] = sv;
            mt[rg] = fmaxf(mt[rg], sv);
          }
        }
      } else {
#pragma unroll
        for (int ni = 0; ni < 4; ++ni)
#pragma unroll
          for (int rg = 0; rg < 4; ++rg) mt[rg] = fmaxf(mt[rg], sacc[ni][rg]);
      }
#pragma unroll
      for (int rg = 0; rg < 4; ++rg) {
        float v = mt[rg];
        v = fmaxf(v, __shfl_xor(v, 1));
        v = fmaxf(v, __shfl_xor(v, 2));
        v = fmaxf(v, __shfl_xor(v, 4));
        v = fmaxf(v, __shfl_xor(v, 8));
        mt[rg] = v;
      }
      float alpha[4], rsum[4];
#pragma unroll
      for (int rg = 0; rg < 4; ++rg) {
        const float mnew = fmaxf(mrun[rg], mt[rg]);
        alpha[rg] = __builtin_exp2f((mrun[rg] - mnew) * SCL2);
        mrun[rg] = mnew;
        rsum[rg] = 0.f;
      }
#pragma unroll
      for (int ni = 0; ni < 4; ++ni)
#pragma unroll
        for (int rg = 0; rg < 4; ++rg) {
          const float pv = __builtin_exp2f((sacc[ni][rg] - mrun[rg]) * SCL2);
          rsum[rg] += pv;
          Ps[(w * 16 + quad * 4 + rg) * LDP + ni * 16 + r] = (bf16)pv;
        }
#pragma unroll
      for (int rg = 0; rg < 4; ++rg) {
        float v = rsum[rg];
        v += __shfl_xor(v, 1);
        v += __shfl_xor(v, 2);
        v += __shfl_xor(v, 4);
        v += __shfl_xor(v, 8);
        lrun[rg] = lrun[rg] * alpha[rg] + v;
      }
#pragma unroll
      for (int di = 0; di < 8; ++di)
#pragma unroll
        for (int rg = 0; rg < 4; ++rg) of[di][rg] *= alpha[rg];

      // --- O += P * V (wave-local Ps rows, no barrier needed)
#pragma unroll
      for (int js = 0; js < 2; ++js) {
        const bf16x8 pf = *(const bf16x8*)(&Ps[(w * 16 + r) * LDP + js * 32 + quad * 8]);
#pragma unroll
        for (int di = 0; di < 8; ++di) {
          const int vrow = di * 16 + r;
          const int vcol = (((js * 4 + quad) ^ ((vrow >> 3) & 7)) << 3);
          const bf16x8 vf = *(const bf16x8*)(&Vt[buf][vrow * LDV + vcol]);
          of[di] = mfma16(pf, vf, of[di]);
        }
      }
    }

    // --- epilogue
#pragma unroll
    for (int rg = 0; rg < 4; ++rg) {
      const float inv = 1.f / lrun[rg];
      const long t = rowq + quad * 4 + rg;
#pragma unroll
      for (int di = 0; di < 8; ++di)
        out[t * 4096 + h * 128 + di * 16 + r] = (bf16)(of[di][rg] * inv);
    }
  }
}

// ---------------- host ----------------
extern "C" void kernel_launch(void* const* d_in, const int* in_sizes, int n_in,
                              void* d_out, int out_size, void* d_ws, size_t ws_size,
                              hipStream_t stream) {
  const int* positions = (const int*)d_in[0];
  const float* hidden = (const float*)d_in[1];
  const float* w_qkv = (const float*)d_in[2];
  const float* w_o = (const float*)d_in[3];
  float* out = (float*)d_out;

  char* ws = (char*)d_ws;
  bf16* hid_b  = (bf16*)(ws);                  // 2048x4096
  bf16* wqkv_b = (bf16*)(ws + 16777216);       // 6144x4096
  bf16* wo_b   = (bf16*)(ws + 67108864);       // 4096x4096
  bf16* qkv    = (bf16*)(ws + 100663296);      // 2048x6144
  bf16* attn   = (bf16*)(ws + 125829120);      // 2048x4096

  cvt3<<<24576, 256, 0, stream>>>(hidden, hid_b, 8388608,
                                  w_qkv, wqkv_b, 25165824,
                                  w_o, wo_b);
  gemm_bt<bf16, 1><<<dim3(48, 16), 256, 0, stream>>>(hid_b, wqkv_b, qkv, 2048, 6144, 4096);
  rope_kernel<<<2560, 256, 0, stream>>>(qkv, positions);
  attn_kernel<<<dim3(16, 32), 256, 0, stream>>>(qkv, attn);
  // split-K=2: 1024 blocks (4/CU); d_out zeroed, blocks accumulate atomically
  hipMemsetAsync(d_out, 0, (size_t)out_size * sizeof(float), stream);
  gemm_bt<float, 2><<<dim3(32, 16, 2), 256, 0, stream>>>(attn, wo_b, out, 2048, 4096, 4096);
}

// Round 5
// 555.527 us; speedup vs baseline: 1.0946x; 1.0946x over previous
//
#include <hip/hip_runtime.h>
#include <hip/hip_bf16.h>
#include <cstdint>

typedef __bf16 bf16;
typedef __bf16 bf16x8 __attribute__((ext_vector_type(8)));
typedef float f32x4 __attribute__((ext_vector_type(4)));

#define DEV __device__ __forceinline__

DEV f32x4 mfma16(bf16x8 a, bf16x8 b, f32x4 c) {
  return __builtin_amdgcn_mfma_f32_16x16x32_bf16(a, b, c, 0, 0, 0);
}

DEV void gl2lds16(const void* g, void* l) {
  __builtin_amdgcn_global_load_lds((__attribute__((address_space(1))) void*)g,
                                   (__attribute__((address_space(3))) void*)l,
                                   16, 0, 0);
}

// ---------------- fused fp32 -> bf16 convert, 3 segments ----------------
DEV void cvt8(const float* __restrict__ s, bf16* __restrict__ d) {
  f32x4 a = *(const f32x4*)(s);
  f32x4 b = *(const f32x4*)(s + 4);
  bf16x8 o;
#pragma unroll
  for (int e = 0; e < 4; ++e) { o[e] = (bf16)a[e]; o[e + 4] = (bf16)b[e]; }
  *(bf16x8*)(d) = o;
}

__global__ void cvt3(const float* __restrict__ s0, bf16* __restrict__ d0, int n0,
                     const float* __restrict__ s1, bf16* __restrict__ d1, int n1,
                     const float* __restrict__ s2, bf16* __restrict__ d2) {
  long i = ((long)blockIdx.x * 256 + threadIdx.x) * 8;
  if (i < n0) { cvt8(s0 + i, d0 + i); return; }
  i -= n0;
  if (i < n1) { cvt8(s1 + i, d1 + i); return; }
  i -= n1;
  cvt8(s2 + i, d2 + i);
}

// ---------------- GEMM C = A(MxK) * B(NxK)^T, BK=64 ----------------
// 128x128 tile, BK=64 (LDS [2 halves][128][32], 32 KB total) -> 32 MFMA per
// barrier-pair (2x the BK=32 amortization). SPLIT>1: blockIdx.z handles a
// K-slice, stores fp32 partials to C + z*M*N (reduced by reduce_add).
template <typename OutT, int SPLIT>
DEV void gemm_body(const bf16* __restrict__ A, const bf16* __restrict__ B,
                   OutT* __restrict__ C, int M, int N, int K) {
  __shared__ bf16 As[2 * 128 * 32];
  __shared__ bf16 Bs[2 * 128 * 32];
  const int tid = threadIdx.x;
  const int lane = tid & 63, w = tid >> 6;
  const int wm = w & 1, wn = w >> 1;
  const int quad = lane >> 4, r = lane & 15;
  const long mBase = (long)blockIdx.y * 128, nBase = (long)blockIdx.x * 128;
  const int Kh = K / SPLIT;
  const int kBeg = blockIdx.z * Kh, kEnd = kBeg + Kh;
  f32x4 acc[4][4];
#pragma unroll
  for (int i = 0; i < 4; ++i)
#pragma unroll
    for (int j = 0; j < 4; ++j) acc[i][j] = f32x4{0.f, 0.f, 0.f, 0.f};

  for (int k0 = kBeg; k0 < kEnd; k0 += 64) {
    __syncthreads();
    // stage 128x64 of A and B: 1024 chunks each; chunk c -> LDS slot c, global
    // (half = c>>9, row = (c>>2)&127, k4 = c&3)
#pragma unroll
    for (int j = 0; j < 4; ++j) {
      const int c = w * 256 + j * 64 + lane;
      const int half = c >> 9, row = (c >> 2) & 127, k4 = c & 3;
      const long koff = k0 + half * 32 + k4 * 8;
      gl2lds16(A + (mBase + row) * (long)K + koff, (char*)As + (w * 256 + j * 64) * 16);
      gl2lds16(B + (nBase + row) * (long)K + koff, (char*)Bs + (w * 256 + j * 64) * 16);
    }
    __syncthreads();
#pragma unroll
    for (int h = 0; h < 2; ++h) {
      bf16x8 af[4], bfr[4];
#pragma unroll
      for (int i = 0; i < 4; ++i) {
        af[i]  = *(const bf16x8*)(&As[h * 4096 + (wm * 64 + i * 16 + r) * 32 + quad * 8]);
        bfr[i] = *(const bf16x8*)(&Bs[h * 4096 + (wn * 64 + i * 16 + r) * 32 + quad * 8]);
      }
#pragma unroll
      for (int mi = 0; mi < 4; ++mi)
#pragma unroll
        for (int ni = 0; ni < 4; ++ni)
          acc[mi][ni] = mfma16(af[mi], bfr[ni], acc[mi][ni]);
    }
  }
  OutT* Cz = C + (size_t)blockIdx.z * M * N;
#pragma unroll
  for (int mi = 0; mi < 4; ++mi)
#pragma unroll
    for (int ni = 0; ni < 4; ++ni)
#pragma unroll
      for (int rg = 0; rg < 4; ++rg) {
        long row = mBase + wm * 64 + mi * 16 + quad * 4 + rg;
        long col = nBase + wn * 64 + ni * 16 + r;
        Cz[row * N + col] = (OutT)acc[mi][ni][rg];
      }
}

__global__ __launch_bounds__(256) void gemm_qkv(const bf16* __restrict__ A,
                                                const bf16* __restrict__ B,
                                                bf16* __restrict__ C, int M, int N, int K) {
  gemm_body<bf16, 1>(A, B, C, M, N, K);
}

__global__ __launch_bounds__(256) void gemm_out2(const bf16* __restrict__ A,
                                                 const bf16* __restrict__ B,
                                                 float* __restrict__ C, int M, int N, int K) {
  gemm_body<float, 2>(A, B, C, M, N, K);
}

// out = p0 + p1 (split-K reduction), 8 fp32/thread
__global__ void reduce_add(const float* __restrict__ p, float* __restrict__ o, int n) {
  const int i = (blockIdx.x * 256 + threadIdx.x) * 8;
  const f32x4 a0 = *(const f32x4*)(p + i),     b0 = *(const f32x4*)(p + n + i);
  const f32x4 a1 = *(const f32x4*)(p + i + 4), b1 = *(const f32x4*)(p + n + i + 4);
  *(f32x4*)(o + i) = a0 + b0;
  *(f32x4*)(o + i + 4) = a1 + b1;
}

// ---------------- RoPE (neox), vectorized bf16x8 ----------------
__global__ void rope_kernel(bf16* __restrict__ qkv, const int* __restrict__ pos) {
  int idx = blockIdx.x * 256 + threadIdx.x;  // T*40*8 threads
  int g = idx & 7;
  int rest = idx >> 3;
  int head = rest % 40;
  int t = rest / 40;
  bf16* p = qkv + (long)t * 6144 + head * 128 + g * 8;
  bf16x8 a = *(const bf16x8*)(p);
  bf16x8 b = *(const bf16x8*)(p + 64);
  const float pf = (float)pos[t];
  bf16x8 oa, ob;
#pragma unroll
  for (int e = 0; e < 8; ++e) {
    const int d = g * 8 + e;
    const float invf = __builtin_expf(-(float)d * (9.210340371976184f / 64.0f));
    const float fr = pf * invf;
    const float c = __builtin_cosf(fr), s = __builtin_sinf(fr);
    const float x1 = (float)a[e], x2 = (float)b[e];
    oa[e] = (bf16)(x1 * c - x2 * s);
    ob[e] = (bf16)(x2 * c + x1 * s);
  }
  *(bf16x8*)(p) = oa;
  *(bf16x8*)(p + 64) = ob;
}

// ---------------- flash attention v4: double-buffered LDS, 1 barrier/tile ----------------
__global__ __launch_bounds__(256, 2) void attn_kernel(const bf16* __restrict__ qkv,
                                                      bf16* __restrict__ out) {
  constexpr int LDV = 72, LDP = 72;
  constexpr float SCL2 = 0.08838834764831845f * 1.4426950408889634f;  // 1/sqrt(128)*log2(e)
  __shared__ bf16 Ks[2][64 * 128];   // [kv][d], chunk-XOR (phys = logical^(row&15))
  __shared__ bf16 Vt[2][128 * LDV];  // V^T [d][kv(+pad)], col-chunk XOR
  __shared__ bf16 Ps[64 * LDP];
  const int tid = threadIdx.x;
  const int lane = tid & 63, w = tid >> 6;
  const int quad = lane >> 4, r = lane & 15;
  const int pr = blockIdx.x, h = blockIdx.y;
  const int kvh = h >> 2;

  bf16x8 kreg[4], vreg[4];
  int srow[4], sdc[4];
#pragma unroll
  for (int ii = 0; ii < 4; ++ii) {
    const int c = ii * 256 + tid;
    srow[ii] = c >> 4;
    sdc[ii] = c & 15;
  }

  for (int which = 0; which < 2; ++which) {
    const int qt = which ? (31 - pr) : pr;
    const int rowq = qt * 64 + w * 16;

    bf16x8 qf[4];
#pragma unroll
    for (int ks = 0; ks < 4; ++ks)
      qf[ks] = *(const bf16x8*)(qkv + (long)(rowq + r) * 6144 + h * 128 + ks * 32 + quad * 8);

    f32x4 of[8];
#pragma unroll
    for (int di = 0; di < 8; ++di) of[di] = f32x4{0.f, 0.f, 0.f, 0.f};
    float mrun[4], lrun[4];
#pragma unroll
    for (int rg = 0; rg < 4; ++rg) { mrun[rg] = -__builtin_inff(); lrun[rg] = 0.f; }

    const int ntiles = qt + 1;
#pragma unroll
    for (int ii = 0; ii < 4; ++ii) {
      const long rb = (long)srow[ii] * 6144 + kvh * 128;
      kreg[ii] = *(const bf16x8*)(qkv + rb + 4096 + sdc[ii] * 8);
      vreg[ii] = *(const bf16x8*)(qkv + rb + 5120 + sdc[ii] * 8);
    }

    for (int kt = 0; kt < ntiles; ++kt) {
      const int kvbase = kt * 64;
      const int buf = kt & 1;
#pragma unroll
      for (int ii = 0; ii < 4; ++ii) {
        const int row = srow[ii], dc = sdc[ii];
        *(bf16x8*)(&Ks[buf][row * 128 + ((dc ^ (row & 15)) << 3)]) = kreg[ii];
        const int pc = (((row >> 3) ^ (dc & 7)) << 3) + (row & 7);
#pragma unroll
        for (int e = 0; e < 8; ++e) Vt[buf][(dc * 8 + e) * LDV + pc] = vreg[ii][e];
      }
      {
        const int kvn = (kt + 1 < ntiles) ? (kt + 1) * 64 : kt * 64;
#pragma unroll
        for (int ii = 0; ii < 4; ++ii) {
          const long rb = (long)(kvn + srow[ii]) * 6144 + kvh * 128;
          kreg[ii] = *(const bf16x8*)(qkv + rb + 4096 + sdc[ii] * 8);
          vreg[ii] = *(const bf16x8*)(qkv + rb + 5120 + sdc[ii] * 8);
        }
      }
      __syncthreads();  // the only barrier per tile

      f32x4 sacc[4];
#pragma unroll
      for (int ni = 0; ni < 4; ++ni) sacc[ni] = f32x4{0.f, 0.f, 0.f, 0.f};
#pragma unroll
      for (int ks = 0; ks < 4; ++ks) {
        bf16x8 kf[4];
#pragma unroll
        for (int ni = 0; ni < 4; ++ni)
          kf[ni] = *(const bf16x8*)(&Ks[buf][(ni * 16 + r) * 128 + (((ks * 4 + quad) ^ r) << 3)]);
#pragma unroll
        for (int ni = 0; ni < 4; ++ni) sacc[ni] = mfma16(qf[ks], kf[ni], sacc[ni]);
      }

      float mt[4];
#pragma unroll
      for (int rg = 0; rg < 4; ++rg) mt[rg] = -1e30f;
      if (kt == qt) {
        const int rq = rowq + quad * 4;
#pragma unroll
        for (int ni = 0; ni < 4; ++ni) {
          const int ck = kvbase + ni * 16 + r;
#pragma unroll
          for (int rg = 0; rg < 4; ++rg) {
            float sv = sacc[ni][rg];
            sv = (ck > rq + rg) ? -1e30f : sv;
            sacc[ni][rg] = sv;
            mt[rg] = fmaxf(mt[rg], sv);
          }
        }
      } else {
#pragma unroll
        for (int ni = 0; ni < 4; ++ni)
#pragma unroll
          for (int rg = 0; rg < 4; ++rg) mt[rg] = fmaxf(mt[rg], sacc[ni][rg]);
      }
#pragma unroll
      for (int rg = 0; rg < 4; ++rg) {
        float v = mt[rg];
        v = fmaxf(v, __shfl_xor(v, 1));
        v = fmaxf(v, __shfl_xor(v, 2));
        v = fmaxf(v, __shfl_xor(v, 4));
        v = fmaxf(v, __shfl_xor(v, 8));
        mt[rg] = v;
      }
      float alpha[4], rsum[4];
#pragma unroll
      for (int rg = 0; rg < 4; ++rg) {
        const float mnew = fmaxf(mrun[rg], mt[rg]);
        alpha[rg] = __builtin_exp2f((mrun[rg] - mnew) * SCL2);
        mrun[rg] = mnew;
        rsum[rg] = 0.f;
      }
#pragma unroll
      for (int ni = 0; ni < 4; ++ni)
#pragma unroll
        for (int rg = 0; rg < 4; ++rg) {
          const float pv = __builtin_exp2f((sacc[ni][rg] - mrun[rg]) * SCL2);
          rsum[rg] += pv;
          Ps[(w * 16 + quad * 4 + rg) * LDP + ni * 16 + r] = (bf16)pv;
        }
#pragma unroll
      for (int rg = 0; rg < 4; ++rg) {
        float v = rsum[rg];
        v += __shfl_xor(v, 1);
        v += __shfl_xor(v, 2);
        v += __shfl_xor(v, 4);
        v += __shfl_xor(v, 8);
        lrun[rg] = lrun[rg] * alpha[rg] + v;
      }
#pragma unroll
      for (int di = 0; di < 8; ++di)
#pragma unroll
        for (int rg = 0; rg < 4; ++rg) of[di][rg] *= alpha[rg];

#pragma unroll
      for (int js = 0; js < 2; ++js) {
        const bf16x8 pf = *(const bf16x8*)(&Ps[(w * 16 + r) * LDP + js * 32 + quad * 8]);
#pragma unroll
        for (int di = 0; di < 8; ++di) {
          const int vrow = di * 16 + r;
          const int vcol = (((js * 4 + quad) ^ ((vrow >> 3) & 7)) << 3);
          const bf16x8 vf = *(const bf16x8*)(&Vt[buf][vrow * LDV + vcol]);
          of[di] = mfma16(pf, vf, of[di]);
        }
      }
    }

#pragma unroll
    for (int rg = 0; rg < 4; ++rg) {
      const float inv = 1.f / lrun[rg];
      const long t = rowq + quad * 4 + rg;
#pragma unroll
      for (int di = 0; di < 8; ++di)
        out[t * 4096 + h * 128 + di * 16 + r] = (bf16)(of[di][rg] * inv);
    }
  }
}

// ---------------- host ----------------
extern "C" void kernel_launch(void* const* d_in, const int* in_sizes, int n_in,
                              void* d_out, int out_size, void* d_ws, size_t ws_size,
                              hipStream_t stream) {
  const int* positions = (const int*)d_in[0];
  const float* hidden = (const float*)d_in[1];
  const float* w_qkv = (const float*)d_in[2];
  const float* w_o = (const float*)d_in[3];
  float* out = (float*)d_out;

  char* ws = (char*)d_ws;
  bf16* hid_b  = (bf16*)(ws);                  // 2048x4096 bf16 (dead after gemm_qkv)
  bf16* wqkv_b = (bf16*)(ws + 16777216);       // 6144x4096 bf16 (dead after gemm_qkv)
  bf16* wo_b   = (bf16*)(ws + 67108864);       // 4096x4096 bf16
  bf16* qkv    = (bf16*)(ws + 100663296);      // 2048x6144 bf16
  bf16* attn   = (bf16*)(ws + 125829120);      // 2048x4096 bf16
  float* part  = (float*)(ws);                 // 2 x 2048x4096 fp32 partials (67.1 MB,
                                               // overlays hid_b/wqkv_b after they die)

  cvt3<<<24576, 256, 0, stream>>>(hidden, hid_b, 8388608,
                                  w_qkv, wqkv_b, 25165824,
                                  w_o, wo_b);
  gemm_qkv<<<dim3(48, 16), 256, 0, stream>>>(hid_b, wqkv_b, qkv, 2048, 6144, 4096);
  rope_kernel<<<2560, 256, 0, stream>>>(qkv, positions);
  attn_kernel<<<dim3(16, 32), 256, 0, stream>>>(qkv, attn);
  gemm_out2<<<dim3(32, 16, 2), 256, 0, stream>>>(attn, wo_b, part, 2048, 4096, 4096);
  reduce_add<<<4096, 256, 0, stream>>>(part, out, 8388608);
}